// Round 3
// baseline (320.013 us; speedup 1.0000x reference)
//
#include <hip/hip_runtime.h>

typedef unsigned short u16;
typedef __bf16 bf16x8 __attribute__((ext_vector_type(8)));
typedef float f32x4 __attribute__((ext_vector_type(4)));

union U8 { ushort4 h4[2]; uint4 q; bf16x8 v; };

__device__ __forceinline__ u16 f2bf(float f) {
    union { float f; unsigned int u; } v; v.f = f;
    unsigned int u = v.u;
    unsigned int r = (u + 0x7FFFu + ((u >> 16) & 1u)) >> 16;
    return (u16)r;
}
__device__ __forceinline__ float bf2f(u16 u) {
    union { unsigned int i; float f; } v;
    v.i = ((unsigned int)u) << 16;
    return v.f;
}
__device__ __forceinline__ float lrelu(float x) { return x > 0.f ? x : 0.01f * x; }

__device__ __forceinline__ f32x4 mfma_(bf16x8 a, bf16x8 b, f32x4 c) {
    return __builtin_amdgcn_mfma_f32_16x16x32_bf16(a, b, c, 0, 0, 0);
}

__device__ __forceinline__ bf16x8 pack8(const float* __restrict__ p) {
    float4 a = *(const float4*)p;
    float4 b = *(const float4*)(p + 4);
    U8 u;
    u.h4[0].x = f2bf(a.x); u.h4[0].y = f2bf(a.y);
    u.h4[0].z = f2bf(a.z); u.h4[0].w = f2bf(a.w);
    u.h4[1].x = f2bf(b.x); u.h4[1].y = f2bf(b.y);
    u.h4[1].z = f2bf(b.z); u.h4[1].w = f2bf(b.w);
    return u.v;
}

__device__ __forceinline__ float dot_f(const float* __restrict__ w,
                                       const float* __restrict__ x, int n) {
    float acc = 0.f;
#pragma unroll 8
    for (int k = 0; k < n; k += 4) {
        float4 a = *(const float4*)(w + k);
        acc += a.x * x[k] + a.y * x[k + 1] + a.z * x[k + 2] + a.w * x[k + 3];
    }
    return acc;
}

// ---------------- Kernel A: the two 32768x256 mat-vecs (HBM-bound) -----------
__global__ __launch_bounds__(256) void big_matvec(
    const float* __restrict__ Wp, const float* __restrict__ bp,
    const float* __restrict__ Wgp, const float* __restrict__ bgp,
    const float* __restrict__ psf, const float* __restrict__ pgf,
    float* __restrict__ cat, float* __restrict__ pg) {
    const int wave = blockIdx.x * 4 + (threadIdx.x >> 6);
    const int NW = gridDim.x * 4;
    const int l = threadIdx.x & 63;
    float4 xa = *(const float4*)(psf + l * 4);
    float4 xg = *(const float4*)(pgf + l * 4);
    for (int r = wave; r < 32768; r += NW) {   // cf rows
        float4 w = *(const float4*)(Wp + (size_t)r * 256 + l * 4);
        float s = w.x * xa.x + w.y * xa.y + w.z * xa.z + w.w * xa.w;
        s += __shfl_xor(s, 1); s += __shfl_xor(s, 2); s += __shfl_xor(s, 4);
        s += __shfl_xor(s, 8); s += __shfl_xor(s, 16); s += __shfl_xor(s, 32);
        if (l == 0) cat[(r >> 8) * 768 + (r & 255)] = lrelu(s + bp[r]);
    }
    for (int r = wave; r < 32768; r += NW) {   // pg rows
        float4 w = *(const float4*)(Wgp + (size_t)r * 256 + l * 4);
        float s = w.x * xg.x + w.y * xg.y + w.z * xg.z + w.w * xg.w;
        s += __shfl_xor(s, 1); s += __shfl_xor(s, 2); s += __shfl_xor(s, 4);
        s += __shfl_xor(s, 8); s += __shfl_xor(s, 16); s += __shfl_xor(s, 32);
        if (l == 0) pg[r] = lrelu(s + bgp[r]);
    }
}

// ------- Stage1: per-node P,Q,An0,Bn0, geo(groupnorm), exists/sem/semins -----
__global__ __launch_bounds__(256) void stage1(
    const float* __restrict__ cat, const float* __restrict__ pg,
    const float* __restrict__ Wel,
    const float* __restrict__ Wgc, const float* __restrict__ bgc,
    const float* __restrict__ gw, const float* __restrict__ gb,
    const float* __restrict__ We, const float* __restrict__ be,
    const float* __restrict__ Ws, const float* __restrict__ bs,
    const float* __restrict__ Wsi, const float* __restrict__ bsi,
    const float* __restrict__ Wne0,
    float* __restrict__ P, float* __restrict__ Q,
    float* __restrict__ An, float* __restrict__ Bn, int* __restrict__ ok,
    float* __restrict__ o_geo, float* __restrict__ o_sem,
    float* __restrict__ o_semins, float* __restrict__ o_exists) {
    __shared__ float cf_s[256], pg_s[256];
    const int i = blockIdx.x, h = threadIdx.x;
    cf_s[h] = cat[i * 768 + h];
    pg_s[h] = pg[i * 256 + h];
    __syncthreads();
    P[i * 256 + h] = dot_f(Wel + h * 512, cf_s, 256);
    Q[i * 256 + h] = dot_f(Wel + h * 512 + 256, cf_s, 256);
    An[i * 256 + h] = dot_f(Wne0 + h * 772, cf_s, 256);
    Bn[i * 256 + h] = dot_f(Wne0 + h * 772 + 256, cf_s, 256);
    // geo branch with group-norm (32 groups of 8 consecutive channels)
    float g = dot_f(Wgc + h * 256, pg_s, 256) + bgc[h];
    float s = g;
    s += __shfl_xor(s, 1); s += __shfl_xor(s, 2); s += __shfl_xor(s, 4);
    float m = s * 0.125f;
    float d = g - m;
    float q2 = d * d;
    q2 += __shfl_xor(q2, 1); q2 += __shfl_xor(q2, 2); q2 += __shfl_xor(q2, 4);
    float var = q2 * 0.125f;
    float xn = d / sqrtf(var + 1e-5f);
    o_geo[i * 256 + h] = lrelu(xn * gw[h] + gb[h]);
    // heads
    if (h < 57) {
        o_sem[i * 57 + h] = dot_f(Ws + h * 256, cf_s, 256) + bs[h];
    } else if (h < 67) {
        int p2 = h - 57;
        o_semins[i * 10 + p2] = dot_f(Wsi + p2 * 256, cf_s, 256) + bsi[p2];
    } else if (h == 67) {
        float e = dot_f(We, cf_s, 256) + be[0];
        o_exists[i] = e;
        ok[i] = (e > 0.f) ? 1 : 0;
    }
}

// ---------- Edge stage: el = lrelu(P_i + Q_j + bel), edge_logits -------------
__global__ __launch_bounds__(256) void edge_k(
    const float* __restrict__ P, const float* __restrict__ Q,
    const float* __restrict__ bel, const float* __restrict__ Wee,
    const float* __restrict__ bee,
    u16* __restrict__ el, float* __restrict__ o_edge) {
    const int pair = blockIdx.x * 4 + (threadIdx.x >> 6);
    const int l = threadIdx.x & 63;
    const int i = pair >> 7, j = pair & 127;
    float4 p = *(const float4*)(P + i * 256 + l * 4);
    float4 q = *(const float4*)(Q + j * 256 + l * 4);
    float4 b = *(const float4*)(bel + l * 4);
    float e0 = lrelu(p.x + q.x + b.x);
    float e1 = lrelu(p.y + q.y + b.y);
    float e2 = lrelu(p.z + q.z + b.z);
    float e3 = lrelu(p.w + q.w + b.w);
    ushort4 st; st.x = f2bf(e0); st.y = f2bf(e1); st.z = f2bf(e2); st.w = f2bf(e3);
    *(ushort4*)(el + (size_t)pair * 256 + l * 4) = st;
    float4 w;
    w = *(const float4*)(Wee + 0 * 256 + l * 4);
    float a0 = e0 * w.x + e1 * w.y + e2 * w.z + e3 * w.w;
    w = *(const float4*)(Wee + 1 * 256 + l * 4);
    float a1 = e0 * w.x + e1 * w.y + e2 * w.z + e3 * w.w;
    w = *(const float4*)(Wee + 2 * 256 + l * 4);
    float a2 = e0 * w.x + e1 * w.y + e2 * w.z + e3 * w.w;
    w = *(const float4*)(Wee + 3 * 256 + l * 4);
    float a3 = e0 * w.x + e1 * w.y + e2 * w.z + e3 * w.w;
#pragma unroll
    for (int mk = 1; mk < 64; mk <<= 1) {
        a0 += __shfl_xor(a0, mk); a1 += __shfl_xor(a1, mk);
        a2 += __shfl_xor(a2, mk); a3 += __shfl_xor(a3, mk);
    }
    if (l == 0) {
        float4 o;
        o.x = a0 + bee[0]; o.y = a1 + bee[1];
        o.z = a2 + bee[2]; o.w = a3 + bee[3];
        *(float4*)(o_edge + (size_t)pair * 4) = o;
    }
}

// ---------- Node transform for iteration 1: An/Bn from x1 --------------------
__global__ __launch_bounds__(256) void node_k(
    const float* __restrict__ cat, int xoff,
    const float* __restrict__ Wne_it,
    float* __restrict__ An, float* __restrict__ Bn) {
    __shared__ float xs[256];
    const int i = blockIdx.x, h = threadIdx.x;
    xs[h] = cat[i * 768 + xoff + h];
    __syncthreads();
    An[i * 256 + h] = dot_f(Wne_it + h * 772, xs, 256);
    Bn[i * 256 + h] = dot_f(Wne_it + h * 772 + 256, xs, 256);
}

// ---------- Message passing: E = el@W3^T via MFMA, fused max-reduce ----------
__global__ __launch_bounds__(256) void mp_k(
    const u16* __restrict__ el, const float* __restrict__ An,
    const float* __restrict__ Bn, const float* __restrict__ Wne_it,
    const float* __restrict__ bne_it, const float* __restrict__ logits,
    const int* __restrict__ ok, float* __restrict__ xout /* stride 768 */) {
    const int i = blockIdx.x;
    const int tid = threadIdx.x;
    if (!ok[i]) { xout[i * 768 + tid] = 0.f; return; }
    const int l = tid & 63, wid = tid >> 6;
    const int lr = l & 15, lq = l >> 4;
    const int h0 = wid * 64;

    bf16x8 bfr[4][8];
    float an[4], bnev[4];
    float4 w4[4];
#pragma unroll
    for (int nt = 0; nt < 4; ++nt) {
        const int h = h0 + nt * 16 + lr;
        const float* wr = Wne_it + h * 772 + 512;
#pragma unroll
        for (int ks = 0; ks < 8; ++ks)
            bfr[nt][ks] = pack8(wr + ks * 32 + lq * 8);
        an[nt] = An[i * 256 + h];
        bnev[nt] = bne_it[h];
        w4[nt] = *(const float4*)(Wne_it + h * 772 + 768);
    }
    unsigned actmask = 0;
    for (int jc = 0; jc < 8; ++jc) {
        int a = 0;
        for (int u = 0; u < 16; ++u) a |= ok[jc * 16 + u];
        if (a) actmask |= (1u << jc);
    }
    float rm0 = -1e30f, rm1 = -1e30f, rm2 = -1e30f, rm3 = -1e30f;
    for (int jc = 0; jc < 8; ++jc) {
        if (!(actmask & (1u << jc))) continue;
        f32x4 acc0{0.f, 0.f, 0.f, 0.f}, acc1{0.f, 0.f, 0.f, 0.f};
        f32x4 acc2{0.f, 0.f, 0.f, 0.f}, acc3{0.f, 0.f, 0.f, 0.f};
#pragma unroll
        for (int ks = 0; ks < 8; ++ks) {
            U8 u;
            u.q = *(const uint4*)(el + (size_t)(i * 128 + jc * 16 + lr) * 256 + ks * 32 + lq * 8);
            bf16x8 af = u.v;
            acc0 = mfma_(af, bfr[0][ks], acc0);
            acc1 = mfma_(af, bfr[1][ks], acc1);
            acc2 = mfma_(af, bfr[2][ks], acc2);
            acc3 = mfma_(af, bfr[3][ks], acc3);
        }
#pragma unroll
        for (int r = 0; r < 4; ++r) {
            const int j = jc * 16 + lq * 4 + r;
            if (!ok[j]) continue;
            float4 lg = *(const float4*)(logits + (size_t)(i * 128 + j) * 4);
            bool any = (lg.x > 0.f) | (lg.y > 0.f) | (lg.z > 0.f) | (lg.w > 0.f);
            if (!any) continue;
            float b0 = Bn[j * 256 + h0 + 0 * 16 + lr];
            float b1 = Bn[j * 256 + h0 + 1 * 16 + lr];
            float b2 = Bn[j * 256 + h0 + 2 * 16 + lr];
            float b3 = Bn[j * 256 + h0 + 3 * 16 + lr];
            float amx0 = -1e30f, amx1 = -1e30f, amx2 = -1e30f, amx3 = -1e30f;
            if (lg.x > 0.f) {
                amx0 = fmaxf(amx0, w4[0].x * lg.x); amx1 = fmaxf(amx1, w4[1].x * lg.x);
                amx2 = fmaxf(amx2, w4[2].x * lg.x); amx3 = fmaxf(amx3, w4[3].x * lg.x);
            }
            if (lg.y > 0.f) {
                amx0 = fmaxf(amx0, w4[0].y * lg.y); amx1 = fmaxf(amx1, w4[1].y * lg.y);
                amx2 = fmaxf(amx2, w4[2].y * lg.y); amx3 = fmaxf(amx3, w4[3].y * lg.y);
            }
            if (lg.z > 0.f) {
                amx0 = fmaxf(amx0, w4[0].z * lg.z); amx1 = fmaxf(amx1, w4[1].z * lg.z);
                amx2 = fmaxf(amx2, w4[2].z * lg.z); amx3 = fmaxf(amx3, w4[3].z * lg.z);
            }
            if (lg.w > 0.f) {
                amx0 = fmaxf(amx0, w4[0].w * lg.w); amx1 = fmaxf(amx1, w4[1].w * lg.w);
                amx2 = fmaxf(amx2, w4[2].w * lg.w); amx3 = fmaxf(amx3, w4[3].w * lg.w);
            }
            rm0 = fmaxf(rm0, lrelu(acc0[r] + an[0] + b0 + bnev[0] + amx0));
            rm1 = fmaxf(rm1, lrelu(acc1[r] + an[1] + b1 + bnev[1] + amx1));
            rm2 = fmaxf(rm2, lrelu(acc2[r] + an[2] + b2 + bnev[2] + amx2));
            rm3 = fmaxf(rm3, lrelu(acc3[r] + an[3] + b3 + bnev[3] + amx3));
        }
    }
    rm0 = fmaxf(rm0, __shfl_xor(rm0, 16)); rm0 = fmaxf(rm0, __shfl_xor(rm0, 32));
    rm1 = fmaxf(rm1, __shfl_xor(rm1, 16)); rm1 = fmaxf(rm1, __shfl_xor(rm1, 32));
    rm2 = fmaxf(rm2, __shfl_xor(rm2, 16)); rm2 = fmaxf(rm2, __shfl_xor(rm2, 32));
    rm3 = fmaxf(rm3, __shfl_xor(rm3, 16)); rm3 = fmaxf(rm3, __shfl_xor(rm3, 32));
    if (lq == 0) {
        xout[i * 768 + h0 + 0 * 16 + lr] = fmaxf(rm0, 0.f);
        xout[i * 768 + h0 + 1 * 16 + lr] = fmaxf(rm1, 0.f);
        xout[i * 768 + h0 + 2 * 16 + lr] = fmaxf(rm2, 0.f);
        xout[i * 768 + h0 + 3 * 16 + lr] = fmaxf(rm3, 0.f);
    }
}

// ---------- Final head: ch = lrelu(cat@Wc^T+bc); child = lrelu(ch@Wc2^T+bc2) -
__global__ __launch_bounds__(256) void head_k(
    const float* __restrict__ cat, const float* __restrict__ Wc,
    const float* __restrict__ bc, const float* __restrict__ Wc2,
    const float* __restrict__ bc2, float* __restrict__ o_child) {
    __shared__ float cs[768];
    __shared__ float ch[256];
    const int i = blockIdx.x, h = threadIdx.x;
    cs[h] = cat[i * 768 + h];
    cs[h + 256] = cat[i * 768 + 256 + h];
    cs[h + 512] = cat[i * 768 + 512 + h];
    __syncthreads();
    float a = dot_f(Wc + h * 768, cs, 768) + bc[h];
    ch[h] = lrelu(a);
    __syncthreads();
    float b = dot_f(Wc2 + h * 256, ch, 256) + bc2[h];
    o_child[i * 256 + h] = lrelu(b);
}

extern "C" void kernel_launch(void* const* d_in, const int* in_sizes, int n_in,
                              void* d_out, int out_size, void* d_ws, size_t ws_size,
                              hipStream_t stream) {
    (void)in_sizes; (void)n_in; (void)out_size; (void)ws_size;
    const float* psf = (const float*)d_in[0];
    const float* pgf = (const float*)d_in[1];
    const float* Wp  = (const float*)d_in[2];
    const float* bp  = (const float*)d_in[3];
    const float* We  = (const float*)d_in[4];
    const float* be  = (const float*)d_in[5];
    const float* Ws  = (const float*)d_in[6];
    const float* bs  = (const float*)d_in[7];
    const float* Wsi = (const float*)d_in[8];
    const float* bsi = (const float*)d_in[9];
    const float* Wel = (const float*)d_in[10];
    const float* bel = (const float*)d_in[11];
    const float* Wee = (const float*)d_in[12];
    const float* bee = (const float*)d_in[13];
    const float* Wne = (const float*)d_in[14];
    const float* bne = (const float*)d_in[15];
    const float* Wc  = (const float*)d_in[16];
    const float* bc  = (const float*)d_in[17];
    const float* Wc2 = (const float*)d_in[18];
    const float* bc2 = (const float*)d_in[19];
    const float* Wgc = (const float*)d_in[20];
    const float* bgc = (const float*)d_in[21];
    const float* Wgp = (const float*)d_in[22];
    const float* bgp = (const float*)d_in[23];
    const float* gw  = (const float*)d_in[24];
    const float* gb  = (const float*)d_in[25];

    float* ws  = (float*)d_ws;
    float* pg  = ws;                 // 32768 f32
    float* cat = ws + 32768;         // 128 x 768 f32 (x0|x1|x2)
    float* P   = ws + 131072;        // 32768 f32
    float* Q   = ws + 163840;        // 32768 f32
    float* An  = ws + 196608;        // 32768 f32
    float* Bn  = ws + 229376;        // 32768 f32
    int*   ok  = (int*)(ws + 262144);    // 128 int
    u16*   el  = (u16*)(ws + 262272);    // 16384 x 256 bf16 (8.39 MB)

    float* out = (float*)d_out;
    float* o_child  = out;
    float* o_geo    = out + 32768;
    float* o_sem    = out + 65536;
    float* o_semins = out + 72832;
    float* o_exists = out + 74112;
    float* o_edge   = out + 74240;

    big_matvec<<<2048, 256, 0, stream>>>(Wp, bp, Wgp, bgp, psf, pgf, cat, pg);
    stage1<<<128, 256, 0, stream>>>(cat, pg, Wel, Wgc, bgc, gw, gb, We, be,
                                    Ws, bs, Wsi, bsi, Wne,
                                    P, Q, An, Bn, ok,
                                    o_geo, o_sem, o_semins, o_exists);
    edge_k<<<4096, 256, 0, stream>>>(P, Q, bel, Wee, bee, el, o_edge);
    mp_k<<<128, 256, 0, stream>>>(el, An, Bn, Wne, bne, o_edge, ok, cat + 256);
    node_k<<<128, 256, 0, stream>>>(cat, 256, Wne + 256 * 772, An, Bn);
    mp_k<<<128, 256, 0, stream>>>(el, An, Bn, Wne + 256 * 772, bne + 256,
                                  o_edge, ok, cat + 512);
    head_k<<<128, 256, 0, stream>>>(cat, Wc, bc, Wc2, bc2, o_child);
}